// Round 1
// baseline (485.635 us; speedup 1.0000x reference)
//
#include <hip/hip_runtime.h>
#include <math.h>

// CTC loss forward: T=1024, N=128, C=256, S=64, L=2S+1=129, blank=0.
constexpr int kT = 1024;
constexpr int kN = 128;
constexpr int kC = 256;
constexpr int kS = 64;
constexpr float NEGV = -1e30f;
constexpr int kStride = 65;  // blank + 64 label slots per (n,t)

__device__ __forceinline__ float lse2(float a, float b) {
    float m = fmaxf(a, b);
    float mn = fminf(a, b);
    return m + __logf(1.0f + __expf(mn - m));
}

__device__ __forceinline__ float lse3(float a, float b, float c) {
    float m = fmaxf(fmaxf(a, b), c);
    float s = __expf(a - m) + __expf(b - m) + __expf(c - m);
    return m + __logf(s);
}

// Kernel 1: per-row logsumexp over C=256, then (GATHER mode) write compact
// log-probs of the 65 needed classes to lpg[n][t][65].
// One wave per row (row = t*N + n); 4 waves per block.
template <bool GATHER>
__global__ __launch_bounds__(256) void k_lse(const float* __restrict__ logits,
                                             const int* __restrict__ y,
                                             float* __restrict__ lpg,
                                             float* __restrict__ lse_out) {
    __shared__ float srow[4][kC];
    const int wid = threadIdx.x >> 6;
    const int lane = threadIdx.x & 63;
    const int row = (blockIdx.x << 2) + wid;  // row = t*kN + n, grid exact
    const int t = row >> 7;                   // / kN (kN == 128)
    const int n = row & (kN - 1);

    const float4 v = reinterpret_cast<const float4*>(logits + (size_t)row * kC)[lane];
    float m = fmaxf(fmaxf(v.x, v.y), fmaxf(v.z, v.w));
#pragma unroll
    for (int o = 32; o > 0; o >>= 1) m = fmaxf(m, __shfl_xor(m, o));
    float s = __expf(v.x - m) + __expf(v.y - m) + __expf(v.z - m) + __expf(v.w - m);
#pragma unroll
    for (int o = 32; o > 0; o >>= 1) s += __shfl_xor(s, o);
    const float lse = m + __logf(s);

    if (GATHER) {
        float* sr = srow[wid];
        reinterpret_cast<float4*>(sr)[lane] = v;
        __syncthreads();
        const int cls = y[(n << 6) + lane];   // labels in [1, C)
        const float val = sr[cls] - lse;
        float* op = lpg + ((size_t)n * kT + t) * kStride;
        op[1 + lane] = val;
        if (lane == 0) op[0] = v.x - lse;     // lane 0 holds element 0 (blank)
    } else {
        if (lane == 0) lse_out[row] = lse;
    }
}

// Kernel 2: alpha recursion. One wave per batch item n.
// Lane l owns states 2l (even/blank: aA) and 2l+1 (odd/label y[l]: aB);
// lane 63 additionally owns state 128 (aC). The only cross-lane term per
// step is old alpha[2l-1] = previous lane's aB -> a single __shfl_up.
template <bool GATHERED, int PF>
__global__ __launch_bounds__(64) void k_dp(const float* __restrict__ lpg,
                                           const float* __restrict__ logits,
                                           const float* __restrict__ lsearr,
                                           const int* __restrict__ y,
                                           const int* __restrict__ xlens,
                                           const int* __restrict__ ylens,
                                           float* __restrict__ nll_out) {
    const int n = blockIdx.x;
    const int l = threadIdx.x;  // 0..63
    const int yl = ylens[n];
    const int xl = xlens[n];
    const int ycur = y[(n << 6) + l];
    const int yprev = __shfl_up(ycur, 1);
    const bool skip = (l >= 1) && (ycur != yprev);  // allow_skip for state 2l+1

    auto load_lp = [&](int t, float& lpb, float& lpy) {
        if (GATHERED) {
            const float* p = lpg + ((size_t)n * kT + t) * kStride;
            lpb = p[0];
            lpy = p[1 + l];
        } else {
            const float* p = logits + ((size_t)t * kN + n) * kC;
            const float d = lsearr[t * kN + n];
            lpb = p[0] - d;
            lpy = p[ycur] - d;
        }
    };

    // t = 0 init: alpha0[0] = lp_blank, alpha0[1] = lp_y0, rest NEG.
    float lpb0, lpy0;
    load_lp(0, lpb0, lpy0);
    float aA = (l == 0) ? lpb0 : NEGV;
    float aB = (l == 0) ? lpy0 : NEGV;
    float aC = NEGV;

    // Register ring of prefetched lp values, statically indexed via unroll.
    float pb[PF], py[PF];
#pragma unroll
    for (int k = 0; k < PF; ++k) load_lp(1 + k, pb[k], py[k]);

    for (int tb = 1; tb < kT; tb += PF) {
#pragma unroll
        for (int k = 0; k < PF; ++k) {
            const int t = tb + k;
            if (t < kT) {
                const float lpb = pb[k];
                const float lpy = py[k];
                if (t + PF < kT) load_lp(t + PF, pb[k], py[k]);

                float am1 = __shfl_up(aB, 1);  // old alpha[2l-1]
                if (l == 0) am1 = NEGV;

                // state 2l (blank): self + from 2l-1 (no skip at blanks)
                const float nA = lpb + lse2(aA, am1);
                // state 2l+1 (label): self + from 2l + optional skip from 2l-1
                const float nB = lpy + lse3(aB, aA, skip ? am1 : NEGV);
                float nC = aC;
                if (l == 63) nC = lpb + lse2(aC, aB);  // state 128 (blank)

                if (t < xl) {  // freeze past xlen (uniform per block)
                    aA = nA;
                    aB = nB;
                    aC = nC;
                }
            }
        }
    }

    // Collect alpha into LDS, lane 0 finishes.
    __shared__ float st[130];
    st[2 * l] = aA;
    st[2 * l + 1] = aB;
    if (l == 63) st[128] = aC;
    __syncthreads();
    if (l == 0) {
        const int end = 2 * yl;  // yl in [16,64] -> end in [32,128]
        const float la = st[end];
        const float lb = st[end - 1];
        float nll = -lse2(la, lb);
        if (!(isfinite(nll) && nll < 1e29f)) nll = 0.0f;  // zero_infinity
        nll_out[n] = nll / (float)yl;
    }
}

__global__ __launch_bounds__(128) void k_reduce(const float* __restrict__ nll,
                                                float* __restrict__ out) {
    const int tid = threadIdx.x;
    float v = nll[tid];
#pragma unroll
    for (int o = 32; o > 0; o >>= 1) v += __shfl_xor(v, o);
    __shared__ float partial[2];
    if ((tid & 63) == 0) partial[tid >> 6] = v;
    __syncthreads();
    if (tid == 0) out[0] = (partial[0] + partial[1]) * (1.0f / (float)kN);
}

extern "C" void kernel_launch(void* const* d_in, const int* in_sizes, int n_in,
                              void* d_out, int out_size, void* d_ws, size_t ws_size,
                              hipStream_t stream) {
    const float* logits = (const float*)d_in[0];
    const int* y = (const int*)d_in[1];
    const int* xlens = (const int*)d_in[2];
    const int* ylens = (const int*)d_in[3];
    float* out = (float*)d_out;

    const size_t need_full = (size_t)kN * kT * kStride * sizeof(float) + kN * sizeof(float);
    const int rows = kT * kN;

    if (ws_size >= need_full) {
        float* lpg = (float*)d_ws;
        float* nll = lpg + (size_t)kN * kT * kStride;
        k_lse<true><<<rows / 4, 256, 0, stream>>>(logits, y, lpg, nullptr);
        k_dp<true, 8><<<kN, 64, 0, stream>>>(lpg, nullptr, nullptr, y, xlens, ylens, nll);
        k_reduce<<<1, kN, 0, stream>>>(nll, out);
    } else {
        // Fallback: store only the per-row logsumexp (2 MB), DP gathers raw
        // logits directly (uncoalesced but correct).
        float* lsearr = (float*)d_ws;
        float* nll = lsearr + (size_t)rows;
        k_lse<false><<<rows / 4, 256, 0, stream>>>(logits, y, nullptr, lsearr);
        k_dp<false, 8><<<kN, 64, 0, stream>>>(nullptr, logits, lsearr, y, xlens, ylens, nll);
        k_reduce<<<1, kN, 0, stream>>>(nll, out);
    }
}

// Round 3
// 177.593 us; speedup vs baseline: 2.7345x; 2.7345x over previous
//
#include <hip/hip_runtime.h>
#include <math.h>

// CTC loss forward: T=1024, N=128, C=256, S=64, L=2S+1=129, blank=0.
constexpr int kT = 1024;
constexpr int kN = 128;
constexpr int kC = 256;
constexpr float NEGV = -1e30f;
constexpr int kStr = 65;              // floats per (n,t): [blank, y0..y63]
constexpr int CHUNK = 64;             // t-steps per staged chunk
constexpr int NCHUNK = kT / CHUNK;    // 16
constexpr int ROWB = kStr * 4;        // 260 B
constexpr int CHUNKB = CHUNK * ROWB;  // 16640 B (multiple of 16)
constexpr float LOG2E = 1.4426950408889634f;
constexpr float LN2 = 0.6931471805599453f;

#if __has_builtin(__builtin_amdgcn_exp2f)
#define EXP2(x) __builtin_amdgcn_exp2f(x)
#else
#define EXP2(x) exp2f(x)
#endif
#if __has_builtin(__builtin_amdgcn_logf)
#define LOG2(x) __builtin_amdgcn_logf(x)
#else
#define LOG2(x) log2f(x)
#endif

__device__ __forceinline__ float lse2_2(float a, float b) {  // log2(2^a + 2^b)
    const float m = fmaxf(a, b);
    const float d = fminf(a, b) - m;
    return m + LOG2(1.0f + EXP2(d));
}

__device__ __forceinline__ float lse2_e(float a, float b) {  // ln(e^a + e^b)
    const float m = fmaxf(a, b);
    return m + __logf(1.0f + __expf(fminf(a, b) - m));
}

__device__ __forceinline__ float lse3_e(float a, float b, float c) {
    const float m = fmaxf(fmaxf(a, b), c);
    return m + __logf(__expf(a - m) + __expf(b - m) + __expf(c - m));
}

// Kernel 1: per-row logsumexp over C=256; GATHER mode writes compact BASE-2
// log-probs of the 65 needed classes to lpg[n][t][65]. One wave per row.
template <bool GATHER>
__global__ __launch_bounds__(256) void k_lse(const float* __restrict__ logits,
                                             const int* __restrict__ y,
                                             float* __restrict__ lpg,
                                             float* __restrict__ lse_out) {
    __shared__ float srow[4][kC];
    const int wid = threadIdx.x >> 6;
    const int lane = threadIdx.x & 63;
    const int row = (blockIdx.x << 2) + wid;  // row = t*kN + n
    const int t = row >> 7;                   // / kN (kN == 128)
    const int n = row & (kN - 1);

    const float4 v = reinterpret_cast<const float4*>(logits + (size_t)row * kC)[lane];
    float m = fmaxf(fmaxf(v.x, v.y), fmaxf(v.z, v.w));
#pragma unroll
    for (int o = 32; o > 0; o >>= 1) m = fmaxf(m, __shfl_xor(m, o));
    float s = __expf(v.x - m) + __expf(v.y - m) + __expf(v.z - m) + __expf(v.w - m);
#pragma unroll
    for (int o = 32; o > 0; o >>= 1) s += __shfl_xor(s, o);

    if (GATHER) {
        const float log2s = LOG2(s);
        float* sr = srow[wid];
        reinterpret_cast<float4*>(sr)[lane] = v;
        __syncthreads();
        const int cls = y[(n << 6) + lane];  // labels in [1, C)
        float* op = lpg + ((size_t)n * kT + t) * kStr;
        op[1 + lane] = (sr[cls] - m) * LOG2E - log2s;
        if (lane == 0) op[0] = (v.x - m) * LOG2E - log2s;  // class 0 (blank)
    } else {
        if (lane == 0) lse_out[row] = m + __logf(s);
    }
}

// Kernel 2 (fast): alpha recursion, base-2 domain. One block per batch item.
// Wave 0 runs the DP (lane l owns states 2l, 2l+1; lane 0 also owns state 128);
// waves 1-3 double-buffer 64-timestep chunks of lpg into LDS via
// global_load_lds. One barrier per chunk. LDS: 2*64*65*4 = 33,280 B (< 64 KiB).
__global__ __launch_bounds__(256) void k_dp_fast(const float* __restrict__ lpg,
                                                 const int* __restrict__ y,
                                                 const int* __restrict__ xlens,
                                                 const int* __restrict__ ylens,
                                                 float* __restrict__ nll_out) {
    __shared__ float sbuf[2][CHUNK * kStr];
    const int n = blockIdx.x;
    const int wid = threadIdx.x >> 6;
    const int l = threadIdx.x & 63;
    const char* src = (const char*)(lpg + (size_t)n * kT * kStr);

    auto stage = [&](int c, int b) {
        const int wbase = (wid - 1) * 64;  // wave-uniform
        const char* gs = src + (size_t)c * CHUNKB;
        char* ls = (char*)&sbuf[b][0];
#pragma unroll
        for (int r = 0; r < (CHUNKB / 16 + 191) / 192; ++r) {
            const int wi = wbase + r * 192;  // wave-uniform word index
            if (wi + l < CHUNKB / 16) {
                __builtin_amdgcn_global_load_lds(
                    (const __attribute__((address_space(1))) void*)(gs + (size_t)(wi + l) * 16),
                    (__attribute__((address_space(3))) void*)(ls + (size_t)wi * 16), 16, 0, 0);
            }
        }
    };

    if (wid > 0) stage(0, 0);
    __syncthreads();

    const int yl = ylens[n];
    const int xl = xlens[n];
    const int ycur = y[(n << 6) + l];
    const int yprev = __shfl_up(ycur, 1);
    const bool skip = (l >= 1) && (ycur != yprev);  // skip into state 2l+1
    const int bpa = ((l + 63) & 63) << 2;           // wrapping lane-1 bpermute addr

    float aA = NEGV, aB = NEGV, aC = NEGV;  // states 2l, 2l+1; lane0: state 128
    if (wid == 0) {
        aA = (l == 0) ? sbuf[0][0] : NEGV;
        aB = (l == 0) ? sbuf[0][1] : NEGV;
    }

    for (int c = 0; c < NCHUNK; ++c) {
        if (wid > 0) {
            if (c + 1 < NCHUNK) stage(c + 1, (c + 1) & 1);
        } else {
            const float* B = sbuf[c & 1];
            constexpr int PF = 4;
            float pb[PF], py[PF];
            const int istart = (c == 0) ? 1 : 0;
#pragma unroll
            for (int k = 0; k < PF; ++k) {
                const int i = istart + k;
                if (i < CHUNK) { pb[k] = B[i * kStr]; py[k] = B[i * kStr + 1 + l]; }
            }
            for (int i0 = istart; i0 < CHUNK; i0 += PF) {
#pragma unroll
                for (int k = 0; k < PF; ++k) {
                    const int i = i0 + k;
                    if (i < CHUNK) {
                        const float lpb = pb[k], lpy = py[k];
                        const int inx = i + PF;
                        if (inx < CHUNK) {
                            pb[k] = B[inx * kStr];
                            py[k] = B[inx * kStr + 1 + l];
                        }
                        // h independent of the shuffle -> issues during bpermute flight
                        const float h = lse2_2(aB, aA);
                        const float am1 = __int_as_float(__builtin_amdgcn_ds_bpermute(
                            bpa, __float_as_int(aB)));  // lane l: aB[l-1]; lane 0: aB[63]
                        // lane 0's lse2 slot computes state 128 (aC, fed by aB[63]);
                        // its own state-0 update is exactly lpb + aA.
                        const float u = (l == 0) ? aC : aA;
                        const float lseA = lse2_2(u, am1);
                        const float nA = lpb + ((l == 0) ? aA : lseA);
                        const float nC = lpb + lseA;  // meaningful at lane 0 only
                        const float nB = lpy + lse2_2(h, skip ? am1 : NEGV);
                        const int t = c * CHUNK + i;
                        if (t < xl) {  // freeze past xlen (uniform per block)
                            aA = nA;
                            aB = nB;
                            aC = nC;
                        }
                    }
                }
            }
        }
        __syncthreads();
    }

    if (wid == 0) {
        // alpha[2*yl] and alpha[2*yl-1]; yl in [16,64]
        const float la = (yl < 64) ? __shfl(aA, yl) : __shfl(aC, 0);
        const float lb = __shfl(aB, yl - 1);
        if (l == 0) {
            float nll = -lse2_2(la, lb) * LN2;  // back to nats
            if (!(isfinite(nll) && nll < 1e29f)) nll = 0.0f;  // zero_infinity
            nll_out[n] = nll / (float)yl;
        }
    }
}

// Fallback DP (no gather workspace): gathers raw logits directly. Slow but correct.
template <int PF>
__global__ __launch_bounds__(64) void k_dp_fb(const float* __restrict__ logits,
                                              const float* __restrict__ lsearr,
                                              const int* __restrict__ y,
                                              const int* __restrict__ xlens,
                                              const int* __restrict__ ylens,
                                              float* __restrict__ nll_out) {
    const int n = blockIdx.x;
    const int l = threadIdx.x;
    const int yl = ylens[n];
    const int xl = xlens[n];
    const int ycur = y[(n << 6) + l];
    const int yprev = __shfl_up(ycur, 1);
    const bool skip = (l >= 1) && (ycur != yprev);

    auto load_lp = [&](int t, float& lpb, float& lpy) {
        const float* p = logits + ((size_t)t * kN + n) * kC;
        const float d = lsearr[t * kN + n];
        lpb = p[0] - d;
        lpy = p[ycur] - d;
    };

    float lpb0, lpy0;
    load_lp(0, lpb0, lpy0);
    float aA = (l == 0) ? lpb0 : NEGV;
    float aB = (l == 0) ? lpy0 : NEGV;
    float aC = NEGV;

    float pb[PF], py[PF];
#pragma unroll
    for (int k = 0; k < PF; ++k) load_lp(1 + k, pb[k], py[k]);

    for (int tb = 1; tb < kT; tb += PF) {
#pragma unroll
        for (int k = 0; k < PF; ++k) {
            const int t = tb + k;
            if (t < kT) {
                const float lpb = pb[k], lpy = py[k];
                if (t + PF < kT) load_lp(t + PF, pb[k], py[k]);
                float am1 = __shfl_up(aB, 1);
                if (l == 0) am1 = NEGV;
                const float nA = lpb + lse2_e(aA, am1);
                const float nB = lpy + lse3_e(aB, aA, skip ? am1 : NEGV);
                float nC = aC;
                if (l == 63) nC = lpb + lse2_e(aC, aB);
                if (t < xl) { aA = nA; aB = nB; aC = nC; }
            }
        }
    }

    __shared__ float st[130];
    st[2 * l] = aA;
    st[2 * l + 1] = aB;
    if (l == 63) st[128] = aC;
    __syncthreads();
    if (l == 0) {
        const int end = 2 * yl;
        float nll = -lse2_e(st[end], st[end - 1]);
        if (!(isfinite(nll) && nll < 1e29f)) nll = 0.0f;
        nll_out[n] = nll / (float)yl;
    }
}

__global__ __launch_bounds__(128) void k_reduce(const float* __restrict__ nll,
                                                float* __restrict__ out) {
    const int tid = threadIdx.x;
    float v = nll[tid];
#pragma unroll
    for (int o = 32; o > 0; o >>= 1) v += __shfl_xor(v, o);
    __shared__ float partial[2];
    if ((tid & 63) == 0) partial[tid >> 6] = v;
    __syncthreads();
    if (tid == 0) out[0] = (partial[0] + partial[1]) * (1.0f / (float)kN);
}

extern "C" void kernel_launch(void* const* d_in, const int* in_sizes, int n_in,
                              void* d_out, int out_size, void* d_ws, size_t ws_size,
                              hipStream_t stream) {
    const float* logits = (const float*)d_in[0];
    const int* y = (const int*)d_in[1];
    const int* xlens = (const int*)d_in[2];
    const int* ylens = (const int*)d_in[3];
    float* out = (float*)d_out;

    const size_t need_full = (size_t)kN * kT * kStr * sizeof(float) + kN * sizeof(float);
    const int rows = kT * kN;

    if (ws_size >= need_full) {
        float* lpg = (float*)d_ws;
        float* nll = lpg + (size_t)kN * kT * kStr;
        k_lse<true><<<rows / 4, 256, 0, stream>>>(logits, y, lpg, nullptr);
        k_dp_fast<<<kN, 256, 0, stream>>>(lpg, y, xlens, ylens, nll);
        k_reduce<<<1, kN, 0, stream>>>(nll, out);
    } else {
        float* lsearr = (float*)d_ws;
        float* nll = lsearr + (size_t)rows;
        k_lse<false><<<rows / 4, 256, 0, stream>>>(logits, y, nullptr, lsearr);
        k_dp_fb<8><<<kN, 64, 0, stream>>>(logits, lsearr, y, xlens, ylens, nll);
        k_reduce<<<1, kN, 0, stream>>>(nll, out);
    }
}